// Round 9
// baseline (712.012 us; speedup 1.0000x reference)
//
#include <hip/hip_runtime.h>
#include <hip/hip_bf16.h>

#define N_NODES 100000
#define N_EDGES 1600000
#define N_EL    200000
// D_IN = D_HID = 128; layer-3 output D = 64. f32 inputs, int32 indices, f32 output.
// Round 9: k_fill/k_hist 8-edges-per-thread ILP batching (fill was latency-bound on
// serialized atomic returns: 1.07 TB/s, VALU 0.5%, occ 70% => neither pipe busy).
// t stays bf16; agg f32.

#define NB_SCAN ((N_NODES + 255) / 256)   // 391
#define EPT 8                              // edges per thread in hist/fill
#define ETHREADS (N_EDGES / EPT)           // 200000 exactly

typedef unsigned int uint32;
typedef unsigned short ushort16;

static __device__ __forceinline__ ushort16 f2bf(float f) {
    uint32 u = __float_as_uint(f);
    u += 0x7fffu + ((u >> 16) & 1u);      // RNE
    return (ushort16)(u >> 16);
}
static __device__ __forceinline__ float bf_lo(uint32 p) { return __uint_as_float(p << 16); }
static __device__ __forceinline__ float bf_hi(uint32 p) { return __uint_as_float(p & 0xffff0000u); }
static __device__ __forceinline__ float bf2f(ushort16 h) { return __uint_as_float((uint32)h << 16); }

// ---------------- degree histogram: 8 fire-and-forget atomics per thread ----------------
__global__ void k_hist(const int* __restrict__ dst, int* __restrict__ degi) {
    int t = blockIdx.x * blockDim.x + threadIdx.x;
    if (t >= ETHREADS) return;
#pragma unroll
    for (int k = 0; k < EPT; ++k)
        atomicAdd(&degi[dst[t + k * ETHREADS]], 1);
}

// ---------------- scan pass 1 (+ dinv) ----------------
__global__ void k_scan1(const int* __restrict__ degi, int* __restrict__ rowptr,
                        int* __restrict__ bsum, float* __restrict__ dinv) {
    __shared__ int s[256];
    int t = threadIdx.x;
    int i = blockIdx.x * 256 + t;
    int v = (i < N_NODES) ? degi[i] : 0;
    if (i < N_NODES) dinv[i] = 1.0f / sqrtf((float)(v + 1));   // +1 self-loop
    s[t] = v;
    __syncthreads();
    for (int off = 1; off < 256; off <<= 1) {
        int u = (t >= off) ? s[t - off] : 0;
        __syncthreads();
        s[t] += u;
        __syncthreads();
    }
    if (i < N_NODES) rowptr[i] = s[t] - v;          // exclusive, local
    if (t == 255) bsum[blockIdx.x] = s[255];
}

__global__ void k_scan2(const int* __restrict__ bsum, int* __restrict__ boff) {
    __shared__ int s[512];
    int t = threadIdx.x;
    int v = (t < NB_SCAN) ? bsum[t] : 0;
    s[t] = v;
    __syncthreads();
    for (int off = 1; off < 512; off <<= 1) {
        int u = (t >= off) ? s[t - off] : 0;
        __syncthreads();
        s[t] += u;
        __syncthreads();
    }
    if (t < NB_SCAN) boff[t] = s[t] - v;            // exclusive
    if (t == NB_SCAN - 1) boff[NB_SCAN] = s[t];     // total
}

__global__ void k_scan3(int* __restrict__ rowptr, const int* __restrict__ boff) {
    int i = blockIdx.x * 256 + threadIdx.x;
    if (i < N_NODES) rowptr[i] += boff[blockIdx.x];
    if (i == 0) rowptr[N_NODES] = boff[NB_SCAN];
}

// ---------------- CSR fill: 8 edges/thread, phased for atomic ILP ----------------
__global__ void k_fill(const int* __restrict__ src, const int* __restrict__ dst,
                       const int* __restrict__ rowptr, int* __restrict__ cursor,
                       int* __restrict__ col) {
    int t = blockIdx.x * blockDim.x + threadIdx.x;
    if (t >= ETHREADS) return;
    int d[EPT], s[EPT], p[EPT];
#pragma unroll
    for (int k = 0; k < EPT; ++k) {
        int e = t + k * ETHREADS;
        d[k] = dst[e];
        s[k] = src[e];
    }
#pragma unroll
    for (int k = 0; k < EPT; ++k)
        p[k] = atomicAdd(&cursor[d[k]], 1);          // 8 independent round-trips in flight
#pragma unroll
    for (int k = 0; k < EPT; ++k) {
        int pos = rowptr[d[k]] + p[k];
        __builtin_nontemporal_store(s[k], &col[pos]);
    }
}

// ---------------- GEMM: C[n,:] = bf16( dinv[n] * (A[n,:128] @ W[128,D]) ) ----------------
template <int D>
__global__ __launch_bounds__(256) void k_gemm_lds(const float* __restrict__ A,
        const float* __restrict__ W, const float* __restrict__ dinv,
        ushort16* __restrict__ C) {
    constexpr int CG = D / 4;
    constexpr int NG = 256 / CG;
    constexpr int NPT = 64 / NG;
    __shared__ float4 sW4[128 * CG];

    int tid = threadIdx.x;
    int cg = tid % CG;
    int ng = tid / CG;
    int n0 = blockIdx.x * 64;

    const float4* W4 = (const float4*)W;
    for (int i = tid; i < 128 * CG; i += 256) sW4[i] = W4[i];
    __syncthreads();

    float4 acc[NPT];
#pragma unroll
    for (int i = 0; i < NPT; ++i) acc[i] = make_float4(0.f, 0.f, 0.f, 0.f);

    const float4* A4 = (const float4*)A;

    for (int k4 = 0; k4 < 32; ++k4) {
        float4 av[NPT];
#pragma unroll
        for (int i = 0; i < NPT; ++i) {
            int n = n0 + ng * NPT + i;
            n = min(n, N_NODES - 1);
            av[i] = A4[(size_t)n * 32 + k4];
        }
        float4 w0 = sW4[(k4 * 4 + 0) * CG + cg];
        float4 w1 = sW4[(k4 * 4 + 1) * CG + cg];
        float4 w2 = sW4[(k4 * 4 + 2) * CG + cg];
        float4 w3 = sW4[(k4 * 4 + 3) * CG + cg];
#pragma unroll
        for (int i = 0; i < NPT; ++i) {
            acc[i].x = fmaf(av[i].x, w0.x, acc[i].x);
            acc[i].y = fmaf(av[i].x, w0.y, acc[i].y);
            acc[i].z = fmaf(av[i].x, w0.z, acc[i].z);
            acc[i].w = fmaf(av[i].x, w0.w, acc[i].w);
            acc[i].x = fmaf(av[i].y, w1.x, acc[i].x);
            acc[i].y = fmaf(av[i].y, w1.y, acc[i].y);
            acc[i].z = fmaf(av[i].y, w1.z, acc[i].z);
            acc[i].w = fmaf(av[i].y, w1.w, acc[i].w);
            acc[i].x = fmaf(av[i].z, w2.x, acc[i].x);
            acc[i].y = fmaf(av[i].z, w2.y, acc[i].y);
            acc[i].z = fmaf(av[i].z, w2.z, acc[i].z);
            acc[i].w = fmaf(av[i].z, w2.w, acc[i].w);
            acc[i].x = fmaf(av[i].w, w3.x, acc[i].x);
            acc[i].y = fmaf(av[i].w, w3.y, acc[i].y);
            acc[i].z = fmaf(av[i].w, w3.z, acc[i].z);
            acc[i].w = fmaf(av[i].w, w3.w, acc[i].w);
        }
    }

#pragma unroll
    for (int i = 0; i < NPT; ++i) {
        int n = n0 + ng * NPT + i;
        if (n < N_NODES) {
            float di = dinv[n];
            float4 o = acc[i];
            uint32 p0 = (uint32)f2bf(o.x * di) | ((uint32)f2bf(o.y * di) << 16);
            uint32 p1 = (uint32)f2bf(o.z * di) | ((uint32)f2bf(o.w * di) << 16);
            uint2 pk; pk.x = p0; pk.y = p1;
            ((uint2*)C)[(size_t)n * (CG) + cg] = pk;
        }
    }
}

// ---------------- gather, D=128: one wave/node, bf16x2/lane, 8x unroll ----------------
template <bool RELU>
__global__ void k_gather128(const int* __restrict__ rowptr, const int* __restrict__ col,
                            const float* __restrict__ dinv, const uint32* __restrict__ t,
                            const float* __restrict__ b, float* __restrict__ outbuf) {
    unsigned wid = (blockIdx.x * blockDim.x + threadIdx.x) >> 6;
    int lane = threadIdx.x & 63;
    if (wid >= N_NODES) return;
    int beg = rowptr[wid], end = rowptr[wid + 1];
    uint32 p = t[(size_t)wid * 64 + lane];
    float ax = bf_lo(p), ay = bf_hi(p);
    int j = beg;
    for (; j + 8 <= end; j += 8) {
        int s0 = col[j], s1 = col[j+1], s2 = col[j+2], s3 = col[j+3];
        int s4 = col[j+4], s5 = col[j+5], s6 = col[j+6], s7 = col[j+7];
        uint32 v0 = t[(size_t)s0 * 64 + lane];
        uint32 v1 = t[(size_t)s1 * 64 + lane];
        uint32 v2 = t[(size_t)s2 * 64 + lane];
        uint32 v3 = t[(size_t)s3 * 64 + lane];
        uint32 v4 = t[(size_t)s4 * 64 + lane];
        uint32 v5 = t[(size_t)s5 * 64 + lane];
        uint32 v6 = t[(size_t)s6 * 64 + lane];
        uint32 v7 = t[(size_t)s7 * 64 + lane];
        ax += (bf_lo(v0) + bf_lo(v1)) + (bf_lo(v2) + bf_lo(v3))
            + ((bf_lo(v4) + bf_lo(v5)) + (bf_lo(v6) + bf_lo(v7)));
        ay += (bf_hi(v0) + bf_hi(v1)) + (bf_hi(v2) + bf_hi(v3))
            + ((bf_hi(v4) + bf_hi(v5)) + (bf_hi(v6) + bf_hi(v7)));
    }
    for (; j + 4 <= end; j += 4) {
        int s0 = col[j], s1 = col[j+1], s2 = col[j+2], s3 = col[j+3];
        uint32 v0 = t[(size_t)s0 * 64 + lane];
        uint32 v1 = t[(size_t)s1 * 64 + lane];
        uint32 v2 = t[(size_t)s2 * 64 + lane];
        uint32 v3 = t[(size_t)s3 * 64 + lane];
        ax += (bf_lo(v0) + bf_lo(v1)) + (bf_lo(v2) + bf_lo(v3));
        ay += (bf_hi(v0) + bf_hi(v1)) + (bf_hi(v2) + bf_hi(v3));
    }
    for (; j < end; ++j) {
        uint32 v = t[(size_t)col[j] * 64 + lane];
        ax += bf_lo(v); ay += bf_hi(v);
    }
    float di = dinv[wid];
    float2 bb = ((const float2*)b)[lane];
    float ox = di * ax + bb.x;
    float oy = di * ay + bb.y;
    if (RELU) { ox = fmaxf(ox, 0.f); oy = fmaxf(oy, 0.f); }
    ((float2*)outbuf)[(size_t)wid * 64 + lane] = make_float2(ox, oy);
}

// ---------------- gather, D=64 ----------------
template <bool RELU>
__global__ void k_gather64(const int* __restrict__ rowptr, const int* __restrict__ col,
                           const float* __restrict__ dinv, const ushort16* __restrict__ t,
                           const float* __restrict__ b, float* __restrict__ outbuf) {
    unsigned wid = (blockIdx.x * blockDim.x + threadIdx.x) >> 6;
    int lane = threadIdx.x & 63;
    if (wid >= N_NODES) return;
    int beg = rowptr[wid], end = rowptr[wid + 1];
    float acc = bf2f(t[(size_t)wid * 64 + lane]);
    int j = beg;
    for (; j + 8 <= end; j += 8) {
        int s0 = col[j], s1 = col[j+1], s2 = col[j+2], s3 = col[j+3];
        int s4 = col[j+4], s5 = col[j+5], s6 = col[j+6], s7 = col[j+7];
        float v0 = bf2f(t[(size_t)s0 * 64 + lane]);
        float v1 = bf2f(t[(size_t)s1 * 64 + lane]);
        float v2 = bf2f(t[(size_t)s2 * 64 + lane]);
        float v3 = bf2f(t[(size_t)s3 * 64 + lane]);
        float v4 = bf2f(t[(size_t)s4 * 64 + lane]);
        float v5 = bf2f(t[(size_t)s5 * 64 + lane]);
        float v6 = bf2f(t[(size_t)s6 * 64 + lane]);
        float v7 = bf2f(t[(size_t)s7 * 64 + lane]);
        acc += (v0 + v1) + (v2 + v3) + ((v4 + v5) + (v6 + v7));
    }
    for (; j + 4 <= end; j += 4) {
        int s0 = col[j], s1 = col[j+1], s2 = col[j+2], s3 = col[j+3];
        acc += (bf2f(t[(size_t)s0 * 64 + lane]) + bf2f(t[(size_t)s1 * 64 + lane]))
             + (bf2f(t[(size_t)s2 * 64 + lane]) + bf2f(t[(size_t)s3 * 64 + lane]));
    }
    for (; j < end; ++j) acc += bf2f(t[(size_t)col[j] * 64 + lane]);
    float o = dinv[wid] * acc + b[lane];
    if (RELU) o = fmaxf(o, 0.f);
    outbuf[(size_t)wid * 64 + lane] = o;
}

// ---------------- decode ----------------
__global__ void k_decode(const int* __restrict__ eli, const float* __restrict__ z,
                         float* __restrict__ out) {
    int e = blockIdx.x * blockDim.x + threadIdx.x;
    if (e >= N_EL) return;
    int a = eli[e];
    int b = eli[N_EL + e];
    const float4* za = (const float4*)(z + (size_t)a * 64);
    const float4* zb = (const float4*)(z + (size_t)b * 64);
    float acc = 0.0f;
#pragma unroll
    for (int i = 0; i < 16; ++i) {
        float4 x = za[i], y = zb[i];
        acc += x.x * y.x + x.y * y.y + x.z * y.z + x.w * y.w;
    }
    out[e] = acc;
}

extern "C" void kernel_launch(void* const* d_in, const int* in_sizes, int n_in,
                              void* d_out, int out_size, void* d_ws, size_t ws_size,
                              hipStream_t stream) {
    const float* x   = (const float*)d_in[0];
    const int*   ei  = (const int*)d_in[1];
    const int*   eli = (const int*)d_in[2];
    const float* W1  = (const float*)d_in[3];
    const float* b1  = (const float*)d_in[4];
    const float* W2  = (const float*)d_in[5];
    const float* b2  = (const float*)d_in[6];
    const float* W3  = (const float*)d_in[7];
    const float* b3  = (const float*)d_in[8];
    float* out = (float*)d_out;

    const int* srcA = ei;
    const int* dstA = ei + N_EDGES;

    // workspace layout (bytes) — non-overlapping (verified):
    //   dinv   [0,          400,000)
    //   degi   [524,288,    924,288)
    //   rowptr [1,048,576,  1,448,580)
    //   cursor [1,507,328,  1,907,328)
    //   bsum   [1,933,312,  1,934,876)
    //   boff   [1,941,504,  1,943,072)
    //   col    [2,097,152,  8,497,152)
    //   t      [ws + 9 MB,  +25.6 MB)   bf16 N x 128
    //   agg    [ws + 40 MB, +51.2 MB)   f32  N x 128
    char* ws = (char*)d_ws;
    float*    dinv   = (float*)   (ws + 0);
    int*      degi   = (int*)     (ws + (512u << 10));
    int*      rowptr = (int*)     (ws + (1024u << 10));
    int*      cursor = (int*)     (ws + (1472u << 10));
    int*      bsum   = (int*)     (ws + (1888u << 10));
    int*      boff   = (int*)     (ws + (1896u << 10));
    int*      col    = (int*)     (ws + (2048u << 10));
    ushort16* t      = (ushort16*)(ws + (9u << 20));
    float*    agg    = (float*)   (ws + (40u << 20));

    const int B = 256;
    const int gEdge = (ETHREADS + B - 1) / B;   // 782
    const int gG  = (N_NODES * 64 + B - 1) / B;
    const int gT  = (N_NODES + 63) / 64;
    const int gEL = (N_EL + B - 1) / B;

    // ---- CSR build ----
    hipMemsetAsync(degi, 0, N_NODES * sizeof(int), stream);
    hipMemsetAsync(cursor, 0, N_NODES * sizeof(int), stream);
    k_hist<<<gEdge, B, 0, stream>>>(dstA, degi);
    k_scan1<<<NB_SCAN, 256, 0, stream>>>(degi, rowptr, bsum, dinv);
    k_scan2<<<1, 512, 0, stream>>>(bsum, boff);
    k_scan3<<<NB_SCAN, 256, 0, stream>>>(rowptr, boff);
    k_fill<<<gEdge, B, 0, stream>>>(srcA, dstA, rowptr, cursor, col);

    // ---- layer 1 ----
    k_gemm_lds<128><<<gT, B, 0, stream>>>(x, W1, dinv, t);
    k_gather128<true><<<gG, B, 0, stream>>>(rowptr, col, dinv, (const uint32*)t, b1, agg);
    // ---- layer 2 ----
    k_gemm_lds<128><<<gT, B, 0, stream>>>(agg, W2, dinv, t);
    k_gather128<true><<<gG, B, 0, stream>>>(rowptr, col, dinv, (const uint32*)t, b2, agg);
    // ---- layer 3 ----
    k_gemm_lds<64><<<gT, B, 0, stream>>>(agg, W3, dinv, t);
    k_gather64<false><<<gG, B, 0, stream>>>(rowptr, col, dinv, t, b3, agg);

    // ---- decode ----
    k_decode<<<gEL, B, 0, stream>>>(eli, agg, out);
}

// Round 10
// 630.714 us; speedup vs baseline: 1.1289x; 1.1289x over previous
//
#include <hip/hip_runtime.h>
#include <hip/hip_bf16.h>

#define N_NODES 100000
#define N_EDGES 1600000
#define N_EL    200000
// D_IN = D_HID = 128; layer-3 output D = 64. f32 inputs, int32 indices, f32 output.
// Round 10: revert EPT batching (occupancy-fed atomics, round-9 lesson).
// CSR build in ONE atomic pass: k_rank records r[e]=atomicAdd(cursor[dst]) and
// cursor doubles as the degree histogram; k_fill2 is atomic-free.

#define NB_SCAN ((N_NODES + 255) / 256)   // 391

typedef unsigned int uint32;
typedef unsigned short ushort16;

static __device__ __forceinline__ ushort16 f2bf(float f) {
    uint32 u = __float_as_uint(f);
    u += 0x7fffu + ((u >> 16) & 1u);      // RNE
    return (ushort16)(u >> 16);
}
static __device__ __forceinline__ float bf_lo(uint32 p) { return __uint_as_float(p << 16); }
static __device__ __forceinline__ float bf_hi(uint32 p) { return __uint_as_float(p & 0xffff0000u); }
static __device__ __forceinline__ float bf2f(ushort16 h) { return __uint_as_float((uint32)h << 16); }

// ---------------- pass 1: rank + histogram in one atomic sweep ----------------
__global__ void k_rank(const int* __restrict__ dst, int* __restrict__ cursor,
                       int* __restrict__ r) {
    int e = blockIdx.x * blockDim.x + threadIdx.x;
    if (e < N_EDGES) r[e] = atomicAdd(&cursor[dst[e]], 1);
}

// ---------------- scan pass 1 (+ dinv); deg comes from cursor ----------------
__global__ void k_scan1(const int* __restrict__ deg, int* __restrict__ rowptr,
                        int* __restrict__ bsum, float* __restrict__ dinv) {
    __shared__ int s[256];
    int t = threadIdx.x;
    int i = blockIdx.x * 256 + t;
    int v = (i < N_NODES) ? deg[i] : 0;
    if (i < N_NODES) dinv[i] = 1.0f / sqrtf((float)(v + 1));   // +1 self-loop
    s[t] = v;
    __syncthreads();
    for (int off = 1; off < 256; off <<= 1) {
        int u = (t >= off) ? s[t - off] : 0;
        __syncthreads();
        s[t] += u;
        __syncthreads();
    }
    if (i < N_NODES) rowptr[i] = s[t] - v;          // exclusive, local
    if (t == 255) bsum[blockIdx.x] = s[255];
}

__global__ void k_scan2(const int* __restrict__ bsum, int* __restrict__ boff) {
    __shared__ int s[512];
    int t = threadIdx.x;
    int v = (t < NB_SCAN) ? bsum[t] : 0;
    s[t] = v;
    __syncthreads();
    for (int off = 1; off < 512; off <<= 1) {
        int u = (t >= off) ? s[t - off] : 0;
        __syncthreads();
        s[t] += u;
        __syncthreads();
    }
    if (t < NB_SCAN) boff[t] = s[t] - v;            // exclusive
    if (t == NB_SCAN - 1) boff[NB_SCAN] = s[t];     // total
}

__global__ void k_scan3(int* __restrict__ rowptr, const int* __restrict__ boff) {
    int i = blockIdx.x * 256 + threadIdx.x;
    if (i < N_NODES) rowptr[i] += boff[blockIdx.x];
    if (i == 0) rowptr[N_NODES] = boff[NB_SCAN];
}

// ---------------- pass 2: atomic-free CSR fill ----------------
__global__ void k_fill2(const int* __restrict__ src, const int* __restrict__ dst,
                        const int* __restrict__ rowptr, const int* __restrict__ r,
                        int* __restrict__ col) {
    int e = blockIdx.x * blockDim.x + threadIdx.x;
    if (e >= N_EDGES) return;
    int pos = rowptr[dst[e]] + r[e];
    __builtin_nontemporal_store(src[e], &col[pos]);
}

// ---------------- GEMM: C[n,:] = bf16( dinv[n] * (A[n,:128] @ W[128,D]) ) ----------------
template <int D>
__global__ __launch_bounds__(256) void k_gemm_lds(const float* __restrict__ A,
        const float* __restrict__ W, const float* __restrict__ dinv,
        ushort16* __restrict__ C) {
    constexpr int CG = D / 4;
    constexpr int NG = 256 / CG;
    constexpr int NPT = 64 / NG;
    __shared__ float4 sW4[128 * CG];

    int tid = threadIdx.x;
    int cg = tid % CG;
    int ng = tid / CG;
    int n0 = blockIdx.x * 64;

    const float4* W4 = (const float4*)W;
    for (int i = tid; i < 128 * CG; i += 256) sW4[i] = W4[i];
    __syncthreads();

    float4 acc[NPT];
#pragma unroll
    for (int i = 0; i < NPT; ++i) acc[i] = make_float4(0.f, 0.f, 0.f, 0.f);

    const float4* A4 = (const float4*)A;

    for (int k4 = 0; k4 < 32; ++k4) {
        float4 av[NPT];
#pragma unroll
        for (int i = 0; i < NPT; ++i) {
            int n = n0 + ng * NPT + i;
            n = min(n, N_NODES - 1);
            av[i] = A4[(size_t)n * 32 + k4];
        }
        float4 w0 = sW4[(k4 * 4 + 0) * CG + cg];
        float4 w1 = sW4[(k4 * 4 + 1) * CG + cg];
        float4 w2 = sW4[(k4 * 4 + 2) * CG + cg];
        float4 w3 = sW4[(k4 * 4 + 3) * CG + cg];
#pragma unroll
        for (int i = 0; i < NPT; ++i) {
            acc[i].x = fmaf(av[i].x, w0.x, acc[i].x);
            acc[i].y = fmaf(av[i].x, w0.y, acc[i].y);
            acc[i].z = fmaf(av[i].x, w0.z, acc[i].z);
            acc[i].w = fmaf(av[i].x, w0.w, acc[i].w);
            acc[i].x = fmaf(av[i].y, w1.x, acc[i].x);
            acc[i].y = fmaf(av[i].y, w1.y, acc[i].y);
            acc[i].z = fmaf(av[i].y, w1.z, acc[i].z);
            acc[i].w = fmaf(av[i].y, w1.w, acc[i].w);
            acc[i].x = fmaf(av[i].z, w2.x, acc[i].x);
            acc[i].y = fmaf(av[i].z, w2.y, acc[i].y);
            acc[i].z = fmaf(av[i].z, w2.z, acc[i].z);
            acc[i].w = fmaf(av[i].z, w2.w, acc[i].w);
            acc[i].x = fmaf(av[i].w, w3.x, acc[i].x);
            acc[i].y = fmaf(av[i].w, w3.y, acc[i].y);
            acc[i].z = fmaf(av[i].w, w3.z, acc[i].z);
            acc[i].w = fmaf(av[i].w, w3.w, acc[i].w);
        }
    }

#pragma unroll
    for (int i = 0; i < NPT; ++i) {
        int n = n0 + ng * NPT + i;
        if (n < N_NODES) {
            float di = dinv[n];
            float4 o = acc[i];
            uint32 p0 = (uint32)f2bf(o.x * di) | ((uint32)f2bf(o.y * di) << 16);
            uint32 p1 = (uint32)f2bf(o.z * di) | ((uint32)f2bf(o.w * di) << 16);
            uint2 pk; pk.x = p0; pk.y = p1;
            ((uint2*)C)[(size_t)n * (CG) + cg] = pk;
        }
    }
}

// ---------------- gather, D=128: one wave/node, bf16x2/lane, 8x unroll ----------------
template <bool RELU>
__global__ void k_gather128(const int* __restrict__ rowptr, const int* __restrict__ col,
                            const float* __restrict__ dinv, const uint32* __restrict__ t,
                            const float* __restrict__ b, float* __restrict__ outbuf) {
    unsigned wid = (blockIdx.x * blockDim.x + threadIdx.x) >> 6;
    int lane = threadIdx.x & 63;
    if (wid >= N_NODES) return;
    int beg = rowptr[wid], end = rowptr[wid + 1];
    uint32 p = t[(size_t)wid * 64 + lane];
    float ax = bf_lo(p), ay = bf_hi(p);
    int j = beg;
    for (; j + 8 <= end; j += 8) {
        int s0 = col[j], s1 = col[j+1], s2 = col[j+2], s3 = col[j+3];
        int s4 = col[j+4], s5 = col[j+5], s6 = col[j+6], s7 = col[j+7];
        uint32 v0 = t[(size_t)s0 * 64 + lane];
        uint32 v1 = t[(size_t)s1 * 64 + lane];
        uint32 v2 = t[(size_t)s2 * 64 + lane];
        uint32 v3 = t[(size_t)s3 * 64 + lane];
        uint32 v4 = t[(size_t)s4 * 64 + lane];
        uint32 v5 = t[(size_t)s5 * 64 + lane];
        uint32 v6 = t[(size_t)s6 * 64 + lane];
        uint32 v7 = t[(size_t)s7 * 64 + lane];
        ax += (bf_lo(v0) + bf_lo(v1)) + (bf_lo(v2) + bf_lo(v3))
            + ((bf_lo(v4) + bf_lo(v5)) + (bf_lo(v6) + bf_lo(v7)));
        ay += (bf_hi(v0) + bf_hi(v1)) + (bf_hi(v2) + bf_hi(v3))
            + ((bf_hi(v4) + bf_hi(v5)) + (bf_hi(v6) + bf_hi(v7)));
    }
    for (; j + 4 <= end; j += 4) {
        int s0 = col[j], s1 = col[j+1], s2 = col[j+2], s3 = col[j+3];
        uint32 v0 = t[(size_t)s0 * 64 + lane];
        uint32 v1 = t[(size_t)s1 * 64 + lane];
        uint32 v2 = t[(size_t)s2 * 64 + lane];
        uint32 v3 = t[(size_t)s3 * 64 + lane];
        ax += (bf_lo(v0) + bf_lo(v1)) + (bf_lo(v2) + bf_lo(v3));
        ay += (bf_hi(v0) + bf_hi(v1)) + (bf_hi(v2) + bf_hi(v3));
    }
    for (; j < end; ++j) {
        uint32 v = t[(size_t)col[j] * 64 + lane];
        ax += bf_lo(v); ay += bf_hi(v);
    }
    float di = dinv[wid];
    float2 bb = ((const float2*)b)[lane];
    float ox = di * ax + bb.x;
    float oy = di * ay + bb.y;
    if (RELU) { ox = fmaxf(ox, 0.f); oy = fmaxf(oy, 0.f); }
    ((float2*)outbuf)[(size_t)wid * 64 + lane] = make_float2(ox, oy);
}

// ---------------- gather, D=64 ----------------
template <bool RELU>
__global__ void k_gather64(const int* __restrict__ rowptr, const int* __restrict__ col,
                           const float* __restrict__ dinv, const ushort16* __restrict__ t,
                           const float* __restrict__ b, float* __restrict__ outbuf) {
    unsigned wid = (blockIdx.x * blockDim.x + threadIdx.x) >> 6;
    int lane = threadIdx.x & 63;
    if (wid >= N_NODES) return;
    int beg = rowptr[wid], end = rowptr[wid + 1];
    float acc = bf2f(t[(size_t)wid * 64 + lane]);
    int j = beg;
    for (; j + 8 <= end; j += 8) {
        int s0 = col[j], s1 = col[j+1], s2 = col[j+2], s3 = col[j+3];
        int s4 = col[j+4], s5 = col[j+5], s6 = col[j+6], s7 = col[j+7];
        float v0 = bf2f(t[(size_t)s0 * 64 + lane]);
        float v1 = bf2f(t[(size_t)s1 * 64 + lane]);
        float v2 = bf2f(t[(size_t)s2 * 64 + lane]);
        float v3 = bf2f(t[(size_t)s3 * 64 + lane]);
        float v4 = bf2f(t[(size_t)s4 * 64 + lane]);
        float v5 = bf2f(t[(size_t)s5 * 64 + lane]);
        float v6 = bf2f(t[(size_t)s6 * 64 + lane]);
        float v7 = bf2f(t[(size_t)s7 * 64 + lane]);
        acc += (v0 + v1) + (v2 + v3) + ((v4 + v5) + (v6 + v7));
    }
    for (; j + 4 <= end; j += 4) {
        int s0 = col[j], s1 = col[j+1], s2 = col[j+2], s3 = col[j+3];
        acc += (bf2f(t[(size_t)s0 * 64 + lane]) + bf2f(t[(size_t)s1 * 64 + lane]))
             + (bf2f(t[(size_t)s2 * 64 + lane]) + bf2f(t[(size_t)s3 * 64 + lane]));
    }
    for (; j < end; ++j) acc += bf2f(t[(size_t)col[j] * 64 + lane]);
    float o = dinv[wid] * acc + b[lane];
    if (RELU) o = fmaxf(o, 0.f);
    outbuf[(size_t)wid * 64 + lane] = o;
}

// ---------------- decode ----------------
__global__ void k_decode(const int* __restrict__ eli, const float* __restrict__ z,
                         float* __restrict__ out) {
    int e = blockIdx.x * blockDim.x + threadIdx.x;
    if (e >= N_EL) return;
    int a = eli[e];
    int b = eli[N_EL + e];
    const float4* za = (const float4*)(z + (size_t)a * 64);
    const float4* zb = (const float4*)(z + (size_t)b * 64);
    float acc = 0.0f;
#pragma unroll
    for (int i = 0; i < 16; ++i) {
        float4 x = za[i], y = zb[i];
        acc += x.x * y.x + x.y * y.y + x.z * y.z + x.w * y.w;
    }
    out[e] = acc;
}

extern "C" void kernel_launch(void* const* d_in, const int* in_sizes, int n_in,
                              void* d_out, int out_size, void* d_ws, size_t ws_size,
                              hipStream_t stream) {
    const float* x   = (const float*)d_in[0];
    const int*   ei  = (const int*)d_in[1];
    const int*   eli = (const int*)d_in[2];
    const float* W1  = (const float*)d_in[3];
    const float* b1  = (const float*)d_in[4];
    const float* W2  = (const float*)d_in[5];
    const float* b2  = (const float*)d_in[6];
    const float* W3  = (const float*)d_in[7];
    const float* b3  = (const float*)d_in[8];
    float* out = (float*)d_out;

    const int* srcA = ei;
    const int* dstA = ei + N_EDGES;

    // workspace layout (bytes) — non-overlapping (verified):
    //   dinv   [0,          400,000)
    //   cursor [524,288,    924,288)    (doubles as degree histogram)
    //   rowptr [1,048,576,  1,448,580)
    //   bsum   [1,933,312,  1,934,876)
    //   boff   [1,941,504,  1,943,072)
    //   col    [2,097,152,  8,497,152)
    //   r      [9 MB,       15.4 MB)
    //   t      [16 MB,      41.6 MB)    bf16 N x 128
    //   agg    [48 MB,      99.2 MB)    f32  N x 128
    char* ws = (char*)d_ws;
    float*    dinv   = (float*)   (ws + 0);
    int*      cursor = (int*)     (ws + (512u << 10));
    int*      rowptr = (int*)     (ws + (1024u << 10));
    int*      bsum   = (int*)     (ws + (1888u << 10));
    int*      boff   = (int*)     (ws + (1896u << 10));
    int*      col    = (int*)     (ws + (2048u << 10));
    int*      r      = (int*)     (ws + (9u << 20));
    ushort16* t      = (ushort16*)(ws + (16u << 20));
    float*    agg    = (float*)   (ws + (48u << 20));

    const int B = 256;
    const int gE  = (N_EDGES + B - 1) / B;
    const int gG  = (N_NODES * 64 + B - 1) / B;
    const int gT  = (N_NODES + 63) / 64;
    const int gEL = (N_EL + B - 1) / B;

    // ---- CSR build (single atomic pass) ----
    hipMemsetAsync(cursor, 0, N_NODES * sizeof(int), stream);
    k_rank<<<gE, B, 0, stream>>>(dstA, cursor, r);
    k_scan1<<<NB_SCAN, 256, 0, stream>>>(cursor, rowptr, bsum, dinv);
    k_scan2<<<1, 512, 0, stream>>>(bsum, boff);
    k_scan3<<<NB_SCAN, 256, 0, stream>>>(rowptr, boff);
    k_fill2<<<gE, B, 0, stream>>>(srcA, dstA, rowptr, r, col);

    // ---- layer 1 ----
    k_gemm_lds<128><<<gT, B, 0, stream>>>(x, W1, dinv, t);
    k_gather128<true><<<gG, B, 0, stream>>>(rowptr, col, dinv, (const uint32*)t, b1, agg);
    // ---- layer 2 ----
    k_gemm_lds<128><<<gT, B, 0, stream>>>(agg, W2, dinv, t);
    k_gather128<true><<<gG, B, 0, stream>>>(rowptr, col, dinv, (const uint32*)t, b2, agg);
    // ---- layer 3 ----
    k_gemm_lds<64><<<gT, B, 0, stream>>>(agg, W3, dinv, t);
    k_gather64<false><<<gG, B, 0, stream>>>(rowptr, col, dinv, t, b3, agg);

    // ---- decode ----
    k_decode<<<gEL, B, 0, stream>>>(eli, agg, out);
}